// Round 10
// baseline (454.160 us; speedup 1.0000x reference)
//
#include <hip/hip_runtime.h>
#include <math.h>

#define BB 4
#define NN 6000
#define BN (BB*NN)      // 24000
#define SS 48
#define PQ (SS*SS)      // 2304
#define TT 550
#define HH 128

#define TPQ 128         // pq tile
#define TTILE 64        // t tile
#define NTILES 9        // ceil(550/64)
#define KT 16           // k chunk
#define SPLITK 8
#define CAP2 BN         // per-tile list capacity
#define MLP_E 64        // electrons per MLP block

__device__ __constant__ float kINV_2PI = 1.0f / (2.0f * 3.14159f);
__device__ __constant__ float kGAUSS_NORM = 0.3989422804f;
#define LOG2E 1.4426950408889634f

__device__ __forceinline__ float fexp2(float x) { return __builtin_amdgcn_exp2f(x); }

// ------------- Kernel 1: MLP + spatial gaussians (merged) -------------
// 64 electrons/block. W2 read from global (L2-hot) -> LDS only 34 KB -> 4 blocks/CU.
__global__ __launch_bounds__(256) void prep_kernel(
    const float* __restrict__ si, const float* __restrict__ mask,
    const float* __restrict__ W1, const float* __restrict__ b1,
    const float* __restrict__ W2, const float* __restrict__ b2,
    const float* __restrict__ W3, const float* __restrict__ b3,
    const float* __restrict__ sensor, const float* __restrict__ el_spread,
    const float* __restrict__ nn_bin_sigma,
    float* __restrict__ GxR, float* __restrict__ Gy)
{
  __shared__ float sh1T[HH][MLP_E];       // 32 KB, [i][e]
  __shared__ float sW1[2 * HH];
  __shared__ float sb1[HH], sb2[HH], sW3[HH];
  __shared__ float sex[MLP_E], sey[MLP_E], sresp[MLP_E], slin[SS];
  int tid = threadIdx.x;
  if (tid < 2 * HH) sW1[tid] = W1[tid];
  if (tid < HH) { sb1[tid] = b1[tid]; sb2[tid] = b2[tid]; sW3[tid] = W3[tid]; }
  if (tid < SS) slin[tid] = sensor[tid * SS * 2];  // lin[p]
  int e0 = blockIdx.x * MLP_E;
  int e = tid & 63;
  float x0 = si[2 * (e0 + e)], x1 = si[2 * (e0 + e) + 1];
  if (tid < MLP_E) { sex[tid] = x0; sey[tid] = x1; }
  __syncthreads();
  // layer 1: each quarter-block covers 32 hidden units for all 64 electrons
  int jb = (tid >> 6) * 32;
  #pragma unroll
  for (int jj = 0; jj < 32; ++jj) {
    int j = jb + jj;
    sh1T[j][e] = fmaxf(x0 * sW1[j] + x1 * sW1[HH + j] + sb1[j], 0.0f);
  }
  __syncthreads();
  // layer 2+3: thread = (e-group of 8) x (4 cols); W2 via global float4
  int c4 = (tid & 31) * 4;
  int eh = tid >> 5;  // 0..7
  float acc[8][4] = {};
  for (int i = 0; i < HH; ++i) {
    float4 w  = *(const float4*)&W2[i * HH + c4];
    float4 ha = *(const float4*)&sh1T[i][eh * 8];
    float4 hb = *(const float4*)&sh1T[i][eh * 8 + 4];
    float hv[8] = {ha.x, ha.y, ha.z, ha.w, hb.x, hb.y, hb.z, hb.w};
    #pragma unroll
    for (int ee = 0; ee < 8; ++ee) {
      acc[ee][0] += hv[ee] * w.x; acc[ee][1] += hv[ee] * w.y;
      acc[ee][2] += hv[ee] * w.z; acc[ee][3] += hv[ee] * w.w;
    }
  }
  float outp[8];
  #pragma unroll
  for (int ee = 0; ee < 8; ++ee) {
    float sacc = 0.0f;
    #pragma unroll
    for (int cc = 0; cc < 4; ++cc)
      sacc += fmaxf(acc[ee][cc] + sb2[c4 + cc], 0.0f) * sW3[c4 + cc];
    outp[ee] = sacc;
  }
  #pragma unroll
  for (int off = 1; off < 32; off <<= 1)
    #pragma unroll
    for (int ee = 0; ee < 8; ++ee)
      outp[ee] += __shfl_xor(outp[ee], off);
  if ((tid & 31) == 0) {
    float b3v = b3[0];
    #pragma unroll
    for (int ee = 0; ee < 8; ++ee) {
      int eidx = e0 + eh * 8 + ee;
      sresp[eh * 8 + ee] = fexp2((outp[ee] + b3v) * LOG2E) * mask[eidx];
    }
  }
  __syncthreads();
  // spatial gaussians for this block's 64 electrons
  float es = el_spread[0];
  float var = es * es;
  float c = (0.5f / var) * LOG2E;
  float sbv = nn_bin_sigma[0];
  float bs = sbv * sbv;
  float amul = (kINV_2PI / var) * (kGAUSS_NORM / sqrtf(bs));
  for (int v = tid; v < MLP_E * SS; v += 256) {
    int ei = v / SS;
    int p = v - ei * SS;
    float lp = slin[p];
    float dx = sex[ei] - lp, dy = sey[ei] - lp;
    GxR[(e0 + ei) * SS + p] = fexp2(-dx * dx * c) * sresp[ei] * amul;
    Gy[(e0 + ei) * SS + p]  = fexp2(-dy * dy * c);
  }
}

// ---------------- Kernel 2: bin electrons (wave-aggregated atomics) ----------
__global__ __launch_bounds__(256) void bin_kernel(
    const float* __restrict__ zpos, const float* __restrict__ nn_bin_sigma,
    int* __restrict__ counts, int* __restrict__ kidx, float* __restrict__ kz)
{
  int bn = blockIdx.x * 256 + threadIdx.x;
  if (bn >= BN) return;  // BN % 64 == 0: whole waves exit together
  float s = nn_bin_sigma[0];
  float bs = s * s;
  float W = ceilf(sqrtf(128.0f * bs));  // drop terms suppressed by <= e^-64
  float z = zpos[bn];
  int jlo = (int)floorf((z - W) * (1.0f / TTILE));
  int jhi = (int)floorf((z + W) * (1.0f / TTILE));
  jlo = jlo < 0 ? 0 : jlo;
  jhi = jhi > NTILES - 1 ? NTILES - 1 : jhi;
  int lane = threadIdx.x & 63;
  for (int j = 0; j < NTILES; ++j) {
    bool c = (j >= jlo) && (j <= jhi);
    unsigned long long m = __ballot(c);
    if (m == 0ull) continue;
    int leader = __ffsll((unsigned long long)m) - 1;
    int base = 0;
    if (lane == leader) base = atomicAdd(&counts[j], __popcll(m));
    base = __shfl(base, leader);
    if (c) {
      int slot = base + __popcll(m & ((1ull << lane) - 1ull));
      kidx[j * CAP2 + slot] = bn;
      kz[j * CAP2 + slot] = z;
    }
  }
}

// ------- Kernel 3: contraction, register-dbuf staging, 1 barrier/chunk -------
__global__ __launch_bounds__(256) void gemm_kernel(
    const float* __restrict__ GxR, const float* __restrict__ Gy,
    const int* __restrict__ counts, const int* __restrict__ kidx,
    const float* __restrict__ kz, const float* __restrict__ nn_bin_sigma,
    float* __restrict__ part)
{
  __shared__ __attribute__((aligned(16))) float Asm[2][KT][TPQ];   // 16 KB
  __shared__ __attribute__((aligned(16))) float Esm[2][KT][TTILE]; // 8 KB

  int tid = threadIdx.x;
  int pqBase = blockIdx.x * TPQ;
  int tileT = blockIdx.y;
  int tBase = tileT * TTILE;
  int bz = blockIdx.z;

  float s = nn_bin_sigma[0];
  float c2 = (0.5f * LOG2E) / (s * s);

  int count = counts[tileT];
  int chunks = (count + KT - 1) / KT;
  int cpsBase = chunks / SPLITK;
  int rem = chunks - cpsBase * SPLITK;
  int myC = cpsBase + (bz < rem ? 1 : 0);
  int chunk0 = bz * cpsBase + (bz < rem ? bz : rem);
  int k0 = chunk0 * KT;
  int kend = k0 + myC * KT;   // may exceed count; guarded

  const int* __restrict__ myidx = kidx + tileT * CAP2;
  const float* __restrict__ myz = kz + tileT * CAP2;

  int aR = tid >> 5;          // A staging row (pass 0); +8 for pass 1
  int aC = (tid & 31) * 4;    // A staging col (16B stride -> conflict-free)
  int eR = tid >> 4;          // E staging row
  int eC = (tid & 15) * 4;    // E staging col
  int tpq = (tid >> 4) * 8;   // compute pq base
  int tt  = (tid & 15) * 4;   // compute t base

  int pqc = pqBase + aC;
  int p0 = pqc / SS,       q0 = pqc - p0 * SS;
  int p1 = (pqc+1) / SS,   q1 = (pqc+1) - p1 * SS;
  int p2 = (pqc+2) / SS,   q2 = (pqc+2) - p2 * SS;
  int p3 = (pqc+3) / SS,   q3 = (pqc+3) - p3 * SS;

  // staging registers (filled by LOAD, flushed by STORE)
  float gx[2][4], gy[2][4];
  bool  kvalid[2];
  float zreg;

  #define LOADC(KC)                                                        \
    {                                                                      \
      _Pragma("unroll")                                                    \
      for (int pass = 0; pass < 2; ++pass) {                               \
        int k = (KC) + aR + pass * 8;                                      \
        bool v = (k < count);                                              \
        kvalid[pass] = v;                                                  \
        int idx = v ? myidx[k] * SS : 0;                                   \
        gx[pass][0] = GxR[idx + p0]; gy[pass][0] = Gy[idx + q0];           \
        gx[pass][1] = GxR[idx + p1]; gy[pass][1] = Gy[idx + q1];           \
        gx[pass][2] = GxR[idx + p2]; gy[pass][2] = Gy[idx + q2];           \
        gx[pass][3] = GxR[idx + p3]; gy[pass][3] = Gy[idx + q3];           \
      }                                                                    \
      int ek = (KC) + eR;                                                  \
      zreg = (ek < count) ? myz[ek] : -1.0e6f; /* exp2 underflows to 0 */  \
    }

  #define STOREC(BUF)                                                     \
    {                                                                     \
      _Pragma("unroll")                                                   \
      for (int pass = 0; pass < 2; ++pass) {                              \
        float m0 = kvalid[pass] ? 1.0f : 0.0f;                            \
        *(float4*)&Asm[BUF][aR + pass * 8][aC] =                          \
            make_float4(gx[pass][0] * gy[pass][0] * m0,                   \
                        gx[pass][1] * gy[pass][1] * m0,                   \
                        gx[pass][2] * gy[pass][2] * m0,                   \
                        gx[pass][3] * gy[pass][3] * m0);                  \
      }                                                                   \
      float d0 = (float)(tBase + eC)     - zreg;                          \
      float d1 = (float)(tBase + eC + 1) - zreg;                          \
      float d2 = (float)(tBase + eC + 2) - zreg;                          \
      float d3 = (float)(tBase + eC + 3) - zreg;                          \
      *(float4*)&Esm[BUF][eR][eC] =                                       \
          make_float4(fexp2(-d0 * d0 * c2), fexp2(-d1 * d1 * c2),         \
                      fexp2(-d2 * d2 * c2), fexp2(-d3 * d3 * c2));        \
    }

  float acc[8][4] = {};

  if (k0 < kend) { LOADC(k0); STOREC(0); }
  __syncthreads();
  int cur = 0;

  for (int kc = k0; kc < kend; kc += KT) {
    bool more = (kc + KT < kend);
    if (more) LOADC(kc + KT);           // issue next chunk's loads early
    #pragma unroll
    for (int k2 = 0; k2 < KT; ++k2) {   // compute current chunk from LDS
      float4 a0 = *(const float4*)&Asm[cur][k2][tpq];
      float4 a1 = *(const float4*)&Asm[cur][k2][tpq + 4];
      float4 e4 = *(const float4*)&Esm[cur][k2][tt];
      float aa[8] = {a0.x, a0.y, a0.z, a0.w, a1.x, a1.y, a1.z, a1.w};
      float ee[4] = {e4.x, e4.y, e4.z, e4.w};
      #pragma unroll
      for (int i2 = 0; i2 < 8; ++i2)
        #pragma unroll
        for (int j2 = 0; j2 < 4; ++j2)
          acc[i2][j2] += aa[i2] * ee[j2];
    }
    if (more) { STOREC(cur ^ 1); cur ^= 1; }
    __syncthreads();
  }

  // plain coalesced partial store (zeros when myC==0)
  float* pb = part + ((tileT * SPLITK + bz) * PQ) * TTILE;
  #pragma unroll
  for (int i = 0; i < 8; ++i) {
    int pq = pqBase + tpq + i;
    *(float4*)&pb[pq * TTILE + tt] =
        make_float4(acc[i][0], acc[i][1], acc[i][2], acc[i][3]);
  }
}

// ---------------- Kernel 4: reduce partials -> out ----------------
__global__ __launch_bounds__(256) void reduce_kernel(
    const float* __restrict__ part, float* __restrict__ out)
{
  int i = blockIdx.x * 256 + threadIdx.x;
  if (i >= PQ * TT) return;
  int pq = i / TT;
  int t = i - pq * TT;
  int tileT = t >> 6;
  int tl = t & 63;
  const float* p = part + ((tileT * SPLITK) * PQ + pq) * TTILE + tl;
  float sum = 0.0f;
  #pragma unroll
  for (int s2 = 0; s2 < SPLITK; ++s2)
    sum += p[s2 * (PQ * TTILE)];
  out[i] = sum;
}

extern "C" void kernel_launch(void* const* d_in, const int* in_sizes, int n_in,
                              void* d_out, int out_size, void* d_ws, size_t ws_size,
                              hipStream_t stream) {
  const float* si     = (const float*)d_in[0];
  const float* zpos   = (const float*)d_in[1];
  const float* mask   = (const float*)d_in[2];
  const float* sensor = (const float*)d_in[3];
  const float* W1     = (const float*)d_in[4];
  const float* b1     = (const float*)d_in[5];
  const float* W2     = (const float*)d_in[6];
  const float* b2     = (const float*)d_in[7];
  const float* W3     = (const float*)d_in[8];
  const float* b3     = (const float*)d_in[9];
  const float* el_spread    = (const float*)d_in[10];
  const float* nn_bin_sigma = (const float*)d_in[11];
  float* out = (float*)d_out;

  float* ws    = (float*)d_ws;
  float* part  = ws;                              // 9*8*2304*64 floats
  float* GxR   = part + NTILES * SPLITK * PQ * TTILE;
  float* Gy    = GxR + BN * SS;                   // 24000*48
  float* kz    = Gy + BN * SS;                    // 9*CAP2
  int*   counts = (int*)(kz + NTILES * CAP2);     // 16
  int*   kidx   = counts + 16;                    // 9*CAP2

  hipMemsetAsync(counts, 0, 16 * sizeof(int), stream);
  prep_kernel<<<BN / MLP_E, 256, 0, stream>>>(si, mask, W1, b1, W2, b2, W3, b3,
                                              sensor, el_spread, nn_bin_sigma, GxR, Gy);
  bin_kernel<<<(BN + 255) / 256, 256, 0, stream>>>(zpos, nn_bin_sigma, counts, kidx, kz);
  gemm_kernel<<<dim3(PQ / TPQ, NTILES, SPLITK), 256, 0, stream>>>(
      GxR, Gy, counts, kidx, kz, nn_bin_sigma, part);
  reduce_kernel<<<(PQ * TT + 255) / 256, 256, 0, stream>>>(part, out);
}

// Round 11
// 320.532 us; speedup vs baseline: 1.4169x; 1.4169x over previous
//
#include <hip/hip_runtime.h>
#include <math.h>

#define BB 4
#define NN 6000
#define BN (BB*NN)      // 24000
#define SS 48
#define PQ (SS*SS)      // 2304
#define TT 550
#define HH 128

#define TPQ 128         // pq tile
#define TTILE 64        // t tile
#define NTILES 9        // ceil(550/64)
#define KT 16           // k chunk
#define SPLITK 8
#define CAP 6144        // slots per tile (expected max ~3900, 1.6x headroom)
#define MLP_E 64        // electrons per block in prep

__device__ __constant__ float kINV_2PI = 1.0f / (2.0f * 3.14159f);
__device__ __constant__ float kGAUSS_NORM = 0.3989422804f;
#define LOG2E 1.4426950408889634f

__device__ __forceinline__ float fexp2(float x) { return __builtin_amdgcn_exp2f(x); }

// ------- Kernel 1: MLP + binning + binned spatial gaussians (merged) -------
// 64 electrons/block. Writes Gx/Gy/z directly into per-tile binned buffers so
// the gemm needs NO index indirection (dense coalesced staging reads).
__global__ __launch_bounds__(256) void prep_kernel(
    const float* __restrict__ si, const float* __restrict__ zpos,
    const float* __restrict__ mask,
    const float* __restrict__ W1, const float* __restrict__ b1,
    const float* __restrict__ W2, const float* __restrict__ b2,
    const float* __restrict__ W3, const float* __restrict__ b3,
    const float* __restrict__ sensor, const float* __restrict__ el_spread,
    const float* __restrict__ nn_bin_sigma,
    int* __restrict__ counts,
    float* __restrict__ GxT, float* __restrict__ GyT, float* __restrict__ zT)
{
  __shared__ float sh1T[HH][MLP_E];       // 32 KB, [i][e]
  __shared__ float sW1[2 * HH];
  __shared__ float sb1[HH], sb2[HH], sW3[HH];
  __shared__ float sex[MLP_E], sey[MLP_E], sresp[MLP_E], slin[SS];
  __shared__ int   sSlot[NTILES][MLP_E];  // slot of electron e in tile j, or -1
  int tid = threadIdx.x;
  if (tid < 2 * HH) sW1[tid] = W1[tid];
  if (tid < HH) { sb1[tid] = b1[tid]; sb2[tid] = b2[tid]; sW3[tid] = W3[tid]; }
  if (tid < SS) slin[tid] = sensor[tid * SS * 2];  // lin[p]
  int e0 = blockIdx.x * MLP_E;
  int e = tid & 63;
  float x0 = si[2 * (e0 + e)], x1 = si[2 * (e0 + e) + 1];
  if (tid < MLP_E) { sex[tid] = x0; sey[tid] = x1; }
  __syncthreads();
  // layer 1: each quarter-block covers 32 hidden units for all 64 electrons
  int jb = (tid >> 6) * 32;
  #pragma unroll
  for (int jj = 0; jj < 32; ++jj) {
    int j = jb + jj;
    sh1T[j][e] = fmaxf(x0 * sW1[j] + x1 * sW1[HH + j] + sb1[j], 0.0f);
  }
  __syncthreads();
  // layer 2+3: thread = (e-group of 8) x (4 cols); W2 via global float4 (L2-hot)
  int c4 = (tid & 31) * 4;
  int eh = tid >> 5;  // 0..7
  float acc[8][4] = {};
  for (int i = 0; i < HH; ++i) {
    float4 w  = *(const float4*)&W2[i * HH + c4];
    float4 ha = *(const float4*)&sh1T[i][eh * 8];
    float4 hb = *(const float4*)&sh1T[i][eh * 8 + 4];
    float hv[8] = {ha.x, ha.y, ha.z, ha.w, hb.x, hb.y, hb.z, hb.w};
    #pragma unroll
    for (int ee = 0; ee < 8; ++ee) {
      acc[ee][0] += hv[ee] * w.x; acc[ee][1] += hv[ee] * w.y;
      acc[ee][2] += hv[ee] * w.z; acc[ee][3] += hv[ee] * w.w;
    }
  }
  float outp[8];
  #pragma unroll
  for (int ee = 0; ee < 8; ++ee) {
    float sacc = 0.0f;
    #pragma unroll
    for (int cc = 0; cc < 4; ++cc)
      sacc += fmaxf(acc[ee][cc] + sb2[c4 + cc], 0.0f) * sW3[c4 + cc];
    outp[ee] = sacc;
  }
  #pragma unroll
  for (int off = 1; off < 32; off <<= 1)
    #pragma unroll
    for (int ee = 0; ee < 8; ++ee)
      outp[ee] += __shfl_xor(outp[ee], off);
  if ((tid & 31) == 0) {
    float b3v = b3[0];
    #pragma unroll
    for (int ee = 0; ee < 8; ++ee) {
      int eidx = e0 + eh * 8 + ee;
      sresp[eh * 8 + ee] = fexp2((outp[ee] + b3v) * LOG2E) * mask[eidx];
    }
  }
  __syncthreads();
  // ---- binning: wave 0 only (64 lanes = 64 electrons), <=9 atomics/block ----
  if (tid < 64) {
    float sbv = nn_bin_sigma[0];
    float bs = sbv * sbv;
    float Wz = ceilf(sqrtf(128.0f * bs));  // drop terms suppressed by <= e^-64
    float z = zpos[e0 + tid];
    int jlo = (int)floorf((z - Wz) * (1.0f / TTILE));
    int jhi = (int)floorf((z + Wz) * (1.0f / TTILE));
    jlo = jlo < 0 ? 0 : jlo;
    jhi = jhi > NTILES - 1 ? NTILES - 1 : jhi;
    int lane = tid;
    for (int j = 0; j < NTILES; ++j) {
      bool c = (j >= jlo) && (j <= jhi);
      unsigned long long m = __ballot(c);
      int s = -1;
      if (m != 0ull) {
        int leader = __ffsll(m) - 1;
        int base = 0;
        if (lane == leader) base = atomicAdd(&counts[j], __popcll(m));
        base = __shfl(base, leader);
        if (c) {
          int slot = base + __popcll(m & ((1ull << lane) - 1ull));
          if (slot < CAP) { s = slot; zT[j * CAP + slot] = z; }
        }
      }
      sSlot[j][lane] = s;
    }
  }
  __syncthreads();
  // ---- spatial gaussians, written straight into binned buffers ----
  float es = el_spread[0];
  float var = es * es;
  float c = (0.5f / var) * LOG2E;
  float sbv = nn_bin_sigma[0];
  float bs = sbv * sbv;
  float amul = (kINV_2PI / var) * (kGAUSS_NORM / sqrtf(bs));
  for (int v = tid; v < MLP_E * SS; v += 256) {
    int ei = v / SS;
    int p = v - ei * SS;
    float lp = slin[p];
    float dx = sex[ei] - lp, dy = sey[ei] - lp;
    float gx = fexp2(-dx * dx * c) * sresp[ei] * amul;
    float gy = fexp2(-dy * dy * c);
    #pragma unroll
    for (int j = 0; j < NTILES; ++j) {
      int s = sSlot[j][ei];
      if (s >= 0) {
        GxT[(j * CAP + s) * SS + p] = gx;
        GyT[(j * CAP + s) * SS + p] = gy;
      }
    }
  }
}

// ------- Kernel 2: contraction from binned buffers (no indirection) -------
__global__ __launch_bounds__(256) void gemm_kernel(
    const float* __restrict__ GxT, const float* __restrict__ GyT,
    const float* __restrict__ zT, const int* __restrict__ counts,
    const float* __restrict__ nn_bin_sigma, float* __restrict__ part)
{
  __shared__ __attribute__((aligned(16))) float Asm[KT][TPQ];   // 8 KB
  __shared__ __attribute__((aligned(16))) float Esm[KT][TTILE]; // 4 KB

  int tid = threadIdx.x;
  int pqBase = blockIdx.x * TPQ;
  int tileT = blockIdx.y;
  int tBase = tileT * TTILE;
  int bz = blockIdx.z;

  float s = nn_bin_sigma[0];
  float c2 = (0.5f * LOG2E) / (s * s);

  int count = counts[tileT];
  if (count > CAP) count = CAP;
  int chunks = (count + KT - 1) / KT;
  int cpsBase = chunks / SPLITK;
  int rem = chunks - cpsBase * SPLITK;
  int myC = cpsBase + (bz < rem ? 1 : 0);
  int chunk0 = bz * cpsBase + (bz < rem ? bz : rem);
  int k0 = chunk0 * KT;
  int kend = k0 + myC * KT;   // may exceed count; guarded below

  const float* __restrict__ Gxb = GxT + tileT * CAP * SS;
  const float* __restrict__ Gyb = GyT + tileT * CAP * SS;
  const float* __restrict__ zb  = zT + tileT * CAP;

  int aR = tid >> 5;          // A staging row (pass 0); +8 for pass 1
  int aC = (tid & 31) * 4;    // A staging col (16B stride -> conflict-free)
  int eR = tid >> 4;          // E staging row
  int eC = (tid & 15) * 4;    // E staging col
  int tpq = (tid >> 4) * 8;   // compute pq base
  int tt  = (tid & 15) * 4;   // compute t base

  int pqc = pqBase + aC;
  int p0 = pqc / SS,       q0 = pqc - p0 * SS;
  int p1 = (pqc+1) / SS,   q1 = (pqc+1) - p1 * SS;
  int p2 = (pqc+2) / SS,   q2 = (pqc+2) - p2 * SS;
  int p3 = (pqc+3) / SS,   q3 = (pqc+3) - p3 * SS;

  float acc[8][4] = {};

  for (int kc = k0; kc < kend; kc += KT) {
    #pragma unroll
    for (int pass = 0; pass < 2; ++pass) {
      int k = kc + aR + pass * 8;
      float4 av = make_float4(0.f, 0.f, 0.f, 0.f);
      if (k < count) {
        const float* gxr = Gxb + k * SS;   // dense row, L1/L2-friendly
        const float* gyr = Gyb + k * SS;
        av.x = gxr[p0] * gyr[q0];
        av.y = gxr[p1] * gyr[q1];
        av.z = gxr[p2] * gyr[q2];
        av.w = gxr[p3] * gyr[q3];
      }
      *(float4*)&Asm[aR + pass * 8][aC] = av;
    }
    {
      int ek = kc + eR;
      float z = (ek < count) ? zb[ek] : -1.0e6f;  // exp2 underflows to 0
      float d0 = (float)(tBase + eC)     - z;
      float d1 = (float)(tBase + eC + 1) - z;
      float d2 = (float)(tBase + eC + 2) - z;
      float d3 = (float)(tBase + eC + 3) - z;
      *(float4*)&Esm[eR][eC] =
          make_float4(fexp2(-d0 * d0 * c2), fexp2(-d1 * d1 * c2),
                      fexp2(-d2 * d2 * c2), fexp2(-d3 * d3 * c2));
    }
    __syncthreads();
    #pragma unroll
    for (int k2 = 0; k2 < KT; ++k2) {
      float4 a0 = *(const float4*)&Asm[k2][tpq];
      float4 a1 = *(const float4*)&Asm[k2][tpq + 4];
      float4 e4 = *(const float4*)&Esm[k2][tt];
      float aa[8] = {a0.x, a0.y, a0.z, a0.w, a1.x, a1.y, a1.z, a1.w};
      float ee[4] = {e4.x, e4.y, e4.z, e4.w};
      #pragma unroll
      for (int i2 = 0; i2 < 8; ++i2)
        #pragma unroll
        for (int j2 = 0; j2 < 4; ++j2)
          acc[i2][j2] += aa[i2] * ee[j2];
    }
    __syncthreads();
  }

  // plain coalesced partial store (zeros when myC==0)
  float* pb = part + ((tileT * SPLITK + bz) * PQ) * TTILE;
  #pragma unroll
  for (int i = 0; i < 8; ++i) {
    int pq = pqBase + tpq + i;
    *(float4*)&pb[pq * TTILE + tt] =
        make_float4(acc[i][0], acc[i][1], acc[i][2], acc[i][3]);
  }
}

// ---------------- Kernel 3: reduce partials -> out ----------------
__global__ __launch_bounds__(256) void reduce_kernel(
    const float* __restrict__ part, float* __restrict__ out)
{
  int i = blockIdx.x * 256 + threadIdx.x;
  if (i >= PQ * TT) return;
  int pq = i / TT;
  int t = i - pq * TT;
  int tileT = t >> 6;
  int tl = t & 63;
  const float* p = part + ((tileT * SPLITK) * PQ + pq) * TTILE + tl;
  float sum = 0.0f;
  #pragma unroll
  for (int s2 = 0; s2 < SPLITK; ++s2)
    sum += p[s2 * (PQ * TTILE)];
  out[i] = sum;
}

extern "C" void kernel_launch(void* const* d_in, const int* in_sizes, int n_in,
                              void* d_out, int out_size, void* d_ws, size_t ws_size,
                              hipStream_t stream) {
  const float* si     = (const float*)d_in[0];
  const float* zpos   = (const float*)d_in[1];
  const float* mask   = (const float*)d_in[2];
  const float* sensor = (const float*)d_in[3];
  const float* W1     = (const float*)d_in[4];
  const float* b1     = (const float*)d_in[5];
  const float* W2     = (const float*)d_in[6];
  const float* b2     = (const float*)d_in[7];
  const float* W3     = (const float*)d_in[8];
  const float* b3     = (const float*)d_in[9];
  const float* el_spread    = (const float*)d_in[10];
  const float* nn_bin_sigma = (const float*)d_in[11];
  float* out = (float*)d_out;

  float* ws    = (float*)d_ws;
  float* part  = ws;                              // 9*8*2304*64 = 10.6M floats
  float* GxT   = part + NTILES * SPLITK * PQ * TTILE;
  float* GyT   = GxT + NTILES * CAP * SS;         // 9*6144*48
  float* zT    = GyT + NTILES * CAP * SS;         // 9*6144
  int*   counts = (int*)(zT + NTILES * CAP);      // 16

  hipMemsetAsync(counts, 0, 16 * sizeof(int), stream);
  prep_kernel<<<BN / MLP_E, 256, 0, stream>>>(si, zpos, mask, W1, b1, W2, b2, W3, b3,
                                              sensor, el_spread, nn_bin_sigma,
                                              counts, GxT, GyT, zT);
  gemm_kernel<<<dim3(PQ / TPQ, NTILES, SPLITK), 256, 0, stream>>>(
      GxT, GyT, zT, counts, nn_bin_sigma, part);
  reduce_kernel<<<(PQ * TT + 255) / 256, 256, 0, stream>>>(part, out);
}

// Round 14
// 291.986 us; speedup vs baseline: 1.5554x; 1.0978x over previous
//
#include <hip/hip_runtime.h>
#include <math.h>

#define BB 4
#define NN 6000
#define BN (BB*NN)      // 24000
#define SS 48
#define PQ (SS*SS)      // 2304
#define TT 550
#define HH 128

#define TPQ 96          // pq tile = 2 p-rows x 48 q  (outer-product aligned)
#define TTILE 64        // t tile
#define NTILES 9        // ceil(550/64)
#define KT 16           // k chunk
#define SPLITK 8
#define CAP 6144        // slots per tile (expected max ~3900, 1.6x headroom)
#define MLP_E 64        // electrons per block in prep

__device__ __constant__ float kINV_2PI = 1.0f / (2.0f * 3.14159f);
__device__ __constant__ float kGAUSS_NORM = 0.3989422804f;
#define LOG2E 1.4426950408889634f

__device__ __forceinline__ float fexp2(float x) { return __builtin_amdgcn_exp2f(x); }

// ------- Kernel 1: MLP + binning + binned spatial gaussians (merged) -------
__global__ __launch_bounds__(256) void prep_kernel(
    const float* __restrict__ si, const float* __restrict__ zpos,
    const float* __restrict__ mask,
    const float* __restrict__ W1, const float* __restrict__ b1,
    const float* __restrict__ W2, const float* __restrict__ b2,
    const float* __restrict__ W3, const float* __restrict__ b3,
    const float* __restrict__ sensor, const float* __restrict__ el_spread,
    const float* __restrict__ nn_bin_sigma,
    int* __restrict__ counts,
    float* __restrict__ GxT, float* __restrict__ GyT, float* __restrict__ zT)
{
  __shared__ float sh1T[HH][MLP_E];       // 32 KB, [i][e]
  __shared__ float sW1[2 * HH];
  __shared__ float sb1[HH], sb2[HH], sW3[HH];
  __shared__ float sex[MLP_E], sey[MLP_E], sresp[MLP_E], slin[SS];
  __shared__ int   sSlot[NTILES][MLP_E];  // slot of electron e in tile j, or -1
  int tid = threadIdx.x;
  if (tid < 2 * HH) sW1[tid] = W1[tid];
  if (tid < HH) { sb1[tid] = b1[tid]; sb2[tid] = b2[tid]; sW3[tid] = W3[tid]; }
  if (tid < SS) slin[tid] = sensor[tid * SS * 2];  // lin[p]
  int e0 = blockIdx.x * MLP_E;
  int e = tid & 63;
  float x0 = si[2 * (e0 + e)], x1 = si[2 * (e0 + e) + 1];
  if (tid < MLP_E) { sex[tid] = x0; sey[tid] = x1; }
  __syncthreads();
  int jb = (tid >> 6) * 32;
  #pragma unroll
  for (int jj = 0; jj < 32; ++jj) {
    int j = jb + jj;
    sh1T[j][e] = fmaxf(x0 * sW1[j] + x1 * sW1[HH + j] + sb1[j], 0.0f);
  }
  __syncthreads();
  int c4 = (tid & 31) * 4;
  int eh = tid >> 5;  // 0..7
  float acc[8][4] = {};
  for (int i = 0; i < HH; ++i) {
    float4 w  = *(const float4*)&W2[i * HH + c4];
    float4 ha = *(const float4*)&sh1T[i][eh * 8];
    float4 hb = *(const float4*)&sh1T[i][eh * 8 + 4];
    float hv[8] = {ha.x, ha.y, ha.z, ha.w, hb.x, hb.y, hb.z, hb.w};
    #pragma unroll
    for (int ee = 0; ee < 8; ++ee) {
      acc[ee][0] += hv[ee] * w.x; acc[ee][1] += hv[ee] * w.y;
      acc[ee][2] += hv[ee] * w.z; acc[ee][3] += hv[ee] * w.w;
    }
  }
  float outp[8];
  #pragma unroll
  for (int ee = 0; ee < 8; ++ee) {
    float sacc = 0.0f;
    #pragma unroll
    for (int cc = 0; cc < 4; ++cc)
      sacc += fmaxf(acc[ee][cc] + sb2[c4 + cc], 0.0f) * sW3[c4 + cc];
    outp[ee] = sacc;
  }
  #pragma unroll
  for (int off = 1; off < 32; off <<= 1)
    #pragma unroll
    for (int ee = 0; ee < 8; ++ee)
      outp[ee] += __shfl_xor(outp[ee], off);
  if ((tid & 31) == 0) {
    float b3v = b3[0];
    #pragma unroll
    for (int ee = 0; ee < 8; ++ee) {
      int eidx = e0 + eh * 8 + ee;
      sresp[eh * 8 + ee] = fexp2((outp[ee] + b3v) * LOG2E) * mask[eidx];
    }
  }
  __syncthreads();
  // ---- binning: wave 0 only, <=9 atomics/block ----
  if (tid < 64) {
    float sbv = nn_bin_sigma[0];
    float bs = sbv * sbv;
    float Wz = ceilf(sqrtf(128.0f * bs));  // drop terms suppressed by <= e^-64
    float z = zpos[e0 + tid];
    int jlo = (int)floorf((z - Wz) * (1.0f / TTILE));
    int jhi = (int)floorf((z + Wz) * (1.0f / TTILE));
    jlo = jlo < 0 ? 0 : jlo;
    jhi = jhi > NTILES - 1 ? NTILES - 1 : jhi;
    int lane = tid;
    for (int j = 0; j < NTILES; ++j) {
      bool c = (j >= jlo) && (j <= jhi);
      unsigned long long m = __ballot(c);
      int s = -1;
      if (m != 0ull) {
        int leader = __ffsll(m) - 1;
        int base = 0;
        if (lane == leader) base = atomicAdd(&counts[j], __popcll(m));
        base = __shfl(base, leader);
        if (c) {
          int slot = base + __popcll(m & ((1ull << lane) - 1ull));
          if (slot < CAP) { s = slot; zT[j * CAP + slot] = z; }
        }
      }
      sSlot[j][lane] = s;
    }
  }
  __syncthreads();
  float es = el_spread[0];
  float var = es * es;
  float c = (0.5f / var) * LOG2E;
  float sbv = nn_bin_sigma[0];
  float bs = sbv * sbv;
  float amul = (kINV_2PI / var) * (kGAUSS_NORM / sqrtf(bs));
  for (int v = tid; v < MLP_E * SS; v += 256) {
    int ei = v / SS;
    int p = v - ei * SS;
    float lp = slin[p];
    float dx = sex[ei] - lp, dy = sey[ei] - lp;
    float gx = fexp2(-dx * dx * c) * sresp[ei] * amul;
    float gy = fexp2(-dy * dy * c);
    #pragma unroll
    for (int j = 0; j < NTILES; ++j) {
      int s = sSlot[j][ei];
      if (s >= 0) {
        GxT[(j * CAP + s) * SS + p] = gx;
        GyT[(j * CAP + s) * SS + p] = gy;
      }
    }
  }
}

// ------- Kernel 2: contraction, outer-product-aligned 96pq x 64t tile -------
// pq tile = 2 p-rows x 48 q. A[k][c] = gx[pBase + (c>=48)] * gy[c%48]: staging
// is float4 gy loads + scalar gx broadcast; no div/mod, no gather.
__global__ __launch_bounds__(256, 8) void gemm_kernel(
    const float* __restrict__ GxT, const float* __restrict__ GyT,
    const float* __restrict__ zT, const int* __restrict__ counts,
    const float* __restrict__ nn_bin_sigma, float* __restrict__ part)
{
  __shared__ __attribute__((aligned(16))) float Asm[KT][TPQ];   // 6 KB
  __shared__ __attribute__((aligned(16))) float Esm[KT][TTILE]; // 4 KB

  int tid = threadIdx.x;
  int pqBase = blockIdx.x * TPQ;
  int pBase = pqBase / SS;    // base p row (2 per block)
  int tileT = blockIdx.y;
  int tBase = tileT * TTILE;
  int bz = blockIdx.z;

  float s = nn_bin_sigma[0];
  float c2 = (0.5f * LOG2E) / (s * s);

  int count = counts[tileT];
  if (count > CAP) count = CAP;
  int chunks = (count + KT - 1) / KT;
  int cpsBase = chunks / SPLITK;
  int rem = chunks - cpsBase * SPLITK;
  int myC = cpsBase + (bz < rem ? 1 : 0);
  int chunk0 = bz * cpsBase + (bz < rem ? bz : rem);
  int k0 = chunk0 * KT;
  int kend = k0 + myC * KT;   // may exceed count; guarded below

  const float* __restrict__ Gxb = GxT + tileT * CAP * SS;
  const float* __restrict__ Gyb = GyT + tileT * CAP * SS;
  const float* __restrict__ zb  = zT + tileT * CAP;

  // A staging decomposition: 16 rows x 24 float4-chunks = 384 chunks.
  // thread stages chunk tid, and chunk tid+256 if tid<128 (loop-invariant).
  int r0 = tid / 24,          c0 = (tid - r0 * 24) * 4;
  int t2 = tid + 256;
  int r1 = t2 / 24,           c1 = (t2 - r1 * 24) * 4;
  int pl0 = (c0 >= SS) ? 1 : 0, ql0 = c0 - pl0 * SS;
  int pl1 = (c1 >= SS) ? 1 : 0, ql1 = c1 - pl1 * SS;

  int eR = tid >> 4;          // E staging row
  int eC = (tid & 15) * 4;    // E staging col
  int tpq = (tid >> 4) * 6;   // compute pq base (6 per thread)
  int tt  = (tid & 15) * 4;   // compute t base

  float acc[6][4] = {};

  for (int kc = k0; kc < kend; kc += KT) {
    {   // chunk A: row r0
      int k = kc + r0;
      float4 av = make_float4(0.f, 0.f, 0.f, 0.f);
      if (k < count) {
        float4 gy = *(const float4*)&Gyb[k * SS + ql0];
        float gxv = Gxb[k * SS + pBase + pl0];
        av = make_float4(gxv * gy.x, gxv * gy.y, gxv * gy.z, gxv * gy.w);
      }
      *(float4*)&Asm[r0][c0] = av;
    }
    if (tid < 128) {  // chunk B: row r1
      int k = kc + r1;
      float4 av = make_float4(0.f, 0.f, 0.f, 0.f);
      if (k < count) {
        float4 gy = *(const float4*)&Gyb[k * SS + ql1];
        float gxv = Gxb[k * SS + pBase + pl1];
        av = make_float4(gxv * gy.x, gxv * gy.y, gxv * gy.z, gxv * gy.w);
      }
      *(float4*)&Asm[r1][c1] = av;
    }
    {   // E staging
      int ek = kc + eR;
      float z = (ek < count) ? zb[ek] : -1.0e6f;  // exp2 underflows to 0
      float d0 = (float)(tBase + eC)     - z;
      float d1 = (float)(tBase + eC + 1) - z;
      float d2 = (float)(tBase + eC + 2) - z;
      float d3 = (float)(tBase + eC + 3) - z;
      *(float4*)&Esm[eR][eC] =
          make_float4(fexp2(-d0 * d0 * c2), fexp2(-d1 * d1 * c2),
                      fexp2(-d2 * d2 * c2), fexp2(-d3 * d3 * c2));
    }
    __syncthreads();
    #pragma unroll
    for (int k2 = 0; k2 < KT; ++k2) {
      float4 a0 = *(const float4*)&Asm[k2][tpq];
      float2 a1 = *(const float2*)&Asm[k2][tpq + 4];
      float4 e4 = *(const float4*)&Esm[k2][tt];
      float aa[6] = {a0.x, a0.y, a0.z, a0.w, a1.x, a1.y};
      float ee[4] = {e4.x, e4.y, e4.z, e4.w};
      #pragma unroll
      for (int i2 = 0; i2 < 6; ++i2)
        #pragma unroll
        for (int j2 = 0; j2 < 4; ++j2)
          acc[i2][j2] += aa[i2] * ee[j2];
    }
    __syncthreads();
  }

  // plain coalesced partial store (zeros when myC==0)
  float* pb = part + ((tileT * SPLITK + bz) * PQ) * TTILE;
  #pragma unroll
  for (int i = 0; i < 6; ++i) {
    int pq = pqBase + tpq + i;
    *(float4*)&pb[pq * TTILE + tt] =
        make_float4(acc[i][0], acc[i][1], acc[i][2], acc[i][3]);
  }
}

// ---------------- Kernel 3: reduce partials -> out ----------------
__global__ __launch_bounds__(256) void reduce_kernel(
    const float* __restrict__ part, float* __restrict__ out)
{
  int i = blockIdx.x * 256 + threadIdx.x;
  if (i >= PQ * TT) return;
  int pq = i / TT;
  int t = i - pq * TT;
  int tileT = t >> 6;
  int tl = t & 63;
  const float* p = part + ((tileT * SPLITK) * PQ + pq) * TTILE + tl;
  float sum = 0.0f;
  #pragma unroll
  for (int s2 = 0; s2 < SPLITK; ++s2)
    sum += p[s2 * (PQ * TTILE)];
  out[i] = sum;
}

extern "C" void kernel_launch(void* const* d_in, const int* in_sizes, int n_in,
                              void* d_out, int out_size, void* d_ws, size_t ws_size,
                              hipStream_t stream) {
  const float* si     = (const float*)d_in[0];
  const float* zpos   = (const float*)d_in[1];
  const float* mask   = (const float*)d_in[2];
  const float* sensor = (const float*)d_in[3];
  const float* W1     = (const float*)d_in[4];
  const float* b1     = (const float*)d_in[5];
  const float* W2     = (const float*)d_in[6];
  const float* b2     = (const float*)d_in[7];
  const float* W3     = (const float*)d_in[8];
  const float* b3     = (const float*)d_in[9];
  const float* el_spread    = (const float*)d_in[10];
  const float* nn_bin_sigma = (const float*)d_in[11];
  float* out = (float*)d_out;

  float* ws    = (float*)d_ws;
  float* part  = ws;                              // 9*8*2304*64 = 10.6M floats
  float* GxT   = part + NTILES * SPLITK * PQ * TTILE;
  float* GyT   = GxT + NTILES * CAP * SS;         // 9*6144*48
  float* zT    = GyT + NTILES * CAP * SS;         // 9*6144
  int*   counts = (int*)(zT + NTILES * CAP);      // 16

  hipMemsetAsync(counts, 0, 16 * sizeof(int), stream);
  prep_kernel<<<BN / MLP_E, 256, 0, stream>>>(si, zpos, mask, W1, b1, W2, b2, W3, b3,
                                              sensor, el_spread, nn_bin_sigma,
                                              counts, GxT, GyT, zT);
  gemm_kernel<<<dim3(PQ / TPQ, NTILES, SPLITK), 256, 0, stream>>>(
      GxT, GyT, zT, counts, nn_bin_sigma, part);
  reduce_kernel<<<(PQ * TT + 255) / 256, 256, 0, stream>>>(part, out);
}